// Round 14
// baseline (175.613 us; speedup 1.0000x reference)
//
#include <hip/hip_runtime.h>
#include <hip/hip_bf16.h>
#include <stdint.h>

// StrideGraphSAGE on MI355X (gfx950).
// h_l = elu(agg @ Wl[l] + bl[l] + nodes @ Wr[l]); out = concat(h_0..h_3, x) along C.
// agg is nonzero only for rows < 1089; edge set = deterministic stride-2 grid.
//
// R14 = R13 core (swapped-operand MFMA dwordx4 nt stores; 128^2, 3-ring,
// counted vmcnt(4), XCD swizzle) + two changes:
// (1) mixed-brow permutation r <-> 68r+1: double-work blocks spread across
//     XCDs AND decode to bids <= 568 (dispatch round 1) -> no 16-step tail.
// (2) gather fused into prep as 18 extra blocks reading x directly (f32,
//     coalesced along n, LDS transpose) -> one dispatch + gap removed.

#define C_DIM 256
#define GRID_G 33
#define N_NODES 1089
#define BATCH 64
#define TOTAL (BATCH * N_NODES)     // 69696
#define M_PAD 69760
#define CN (C_DIM * N_NODES)        // 278784
#define OUT_STRIDE_B (5 * CN)       // 1393920
#define NCOLS 1024
#define AGG_ROWS 1152               // 9 tiles of 128; rows 1089..1151 zeroed

using bf16 = __hip_bfloat16;
typedef __attribute__((ext_vector_type(8))) short short8;
typedef __attribute__((ext_vector_type(4))) float f32x4;

// ---- workspace layout (bytes) ----
#define NODES_BYTES ((size_t)M_PAD * C_DIM * 2)
#define OFF_NODES   ((size_t)0)
#define OFF_AGGB    (NODES_BYTES)
#define AGGB_BYTES  ((size_t)AGG_ROWS * C_DIM * 2)
#define OFF_WLT     (OFF_AGGB + AGGB_BYTES)
#define WT_BYTES    ((size_t)NCOLS * C_DIM * 2)
#define OFF_WRT     (OFF_WLT + WT_BYTES)

__device__ __forceinline__ void gload16(void* lds, const void* g) {
    __builtin_amdgcn_global_load_lds(
        (const __attribute__((address_space(1))) uint32_t*)g,
        (__attribute__((address_space(3))) uint32_t*)lds,
        16, 0, 0);
}

// ---- fused prep ----
// blocks [0,128):    W[l][k][c] f32 -> WT[l*256+c][k] bf16
// blocks [128,1280): x [B,C,N] f32 -> nodes [B*N,C] bf16 + copy x into out block 4
// blocks [1280,1298): analytic mean-aggregate from x (batch 0) -> aggb bf16,
//                     rows >= N_NODES zeroed (block 17 covers 1089..1151)
__global__ __launch_bounds__(256)
void prep_kernel(const float* __restrict__ x,
                 const float* __restrict__ Wl, const float* __restrict__ Wr,
                 bf16* __restrict__ nodes, bf16* __restrict__ WlT, bf16* __restrict__ WrT,
                 bf16* __restrict__ aggb, float* __restrict__ out)
{
    __shared__ char smem[33792];
    const int t = threadIdx.x;
    const int bid = blockIdx.x;
    if (bid < 128) {
        float (*tile)[65] = (float(*)[65])smem;
        const int sel = bid & 1;
        const int l = (bid >> 1) & 3;
        const int kt = ((bid >> 3) & 3) * 64;
        const int ct = ((bid >> 5) & 3) * 64;
        const float* W = sel ? Wr : Wl;
        bf16* WT = sel ? WrT : WlT;
        const int tc = t & 63;
        const int tk = t >> 6;
#pragma unroll
        for (int i = 0; i < 16; ++i) {
            int kl = i * 4 + tk;
            tile[kl][tc] = W[((size_t)(l * 256 + kt + kl)) * 256 + ct + tc];
        }
        __syncthreads();
#pragma unroll
        for (int i = 0; i < 16; ++i) {
            int cl = i * 4 + tk;
            WT[((size_t)(l * 256 + ct + cl)) * 256 + kt + tc] = __float2bfloat16(tile[tc][cl]);
        }
    } else if (bid < 1280) {
        bf16 (*tile)[66] = (bf16(*)[66])smem;
        const int bid2 = bid - 128;
        const int b = bid2 / 18;
        const int n0 = (bid2 % 18) * 64;
        const int nl = t & 63;
        const int cs = t >> 6;
        const int n = n0 + nl;
        const bool nvalid = n < N_NODES;
        const float* xb = x + (size_t)b * CN;
        float* outb = out + (size_t)b * OUT_STRIDE_B + (size_t)4 * CN;
#pragma unroll 4
        for (int cc = 0; cc < 64; ++cc) {
            int c = cc * 4 + cs;
            if (nvalid) {
                float v = xb[(size_t)c * N_NODES + n];
                __builtin_nontemporal_store(v, &outb[(size_t)c * N_NODES + n]);
                tile[c][nl] = __float2bfloat16(v);
            }
        }
        __syncthreads();
        const int half = t >> 7;
        const int c0 = (t & 127) * 2;
#pragma unroll
        for (int it = 0; it < 32; ++it) {
            int row = it * 2 + half;
            int nr = n0 + row;
            if (nr < N_NODES) {
                __hip_bfloat162 p;
                p.x = tile[c0][row];
                p.y = tile[c0 + 1][row];
                *(__hip_bfloat162*)(nodes + ((size_t)b * N_NODES + nr) * C_DIM + c0) = p;
            }
        }
    } else {
        // ---- gather-from-x: agg[n][c] = mean of x[0][c][nbr] ----
        bf16 (*tile)[66] = (bf16(*)[66])smem;
        const int n0 = (bid - 1280) * 64;
        const int nl = t & 63;
        const int cs = t >> 6;
        const int n = n0 + nl;
        const bool nvalid = n < N_NODES;
        const int gi = nvalid ? n / GRID_G : 0;
        const int gj = nvalid ? n - gi * GRID_G : 0;
        const bool f1 = nvalid && (gj >= 2);
        const bool f2 = nvalid && (gi >= 2);
        const bool f3 = f2 && (gj >= 2);
        const bool f4 = f2 && (gj >= 1) && (gj <= 30);
        const float dg = (f1 ? 1.f : 0.f) + (f2 ? 1.f : 0.f) +
                         (f3 ? 1.f : 0.f) + (f4 ? 1.f : 0.f);
        const float inv = dg > 0.f ? 1.f / dg : 0.f;
#pragma unroll 4
        for (int cc = 0; cc < 64; ++cc) {
            int c = cc * 4 + cs;
            const float* xc = x + (size_t)c * N_NODES;
            float s = 0.f;
            if (f1) s += xc[n - 2];
            if (f2) s += xc[n - 66];
            if (f3) s += xc[n - 68];
            if (f4) s += xc[n - 64];
            tile[c][nl] = __float2bfloat16(s * inv);
        }
        __syncthreads();
        const int half = t >> 7;
        const int c0 = (t & 127) * 2;
#pragma unroll
        for (int it = 0; it < 32; ++it) {
            int row = it * 2 + half;
            int nr = n0 + row;   // always < AGG_ROWS; pad rows get zeros (tile init'd 0 via f-flags)
            __hip_bfloat162 p;
            p.x = tile[c0][row];
            p.y = tile[c0 + 1][row];
            *(__hip_bfloat162*)(aggb + ((size_t)nr) * C_DIM + c0) = p;
        }
    }
}

// ---- fused GEMM: out = elu(nodes@WrT^T + [agg@WlT^T] + bias), dwordx4 stores ----
// 128x128 tile, 4 waves, 16x16x32 bf16 MFMA. 3-buffer LDS, 2-deep prefetch,
// counted s_waitcnt vmcnt(4) + raw s_barrier. XOR-swizzled LDS both-sides.
// XCD-aware block swizzle + early-dispatch mixed-brow permutation (r <-> 68r+1).
// MFMA operands swapped: acc[m][n] f32x4 = out[row brow*128+wr+m*16+fr]
// [cols bcol*128+wc+n*16+kq*4 .. +3] -> dwordx4 nontemporal stores.
__global__ __launch_bounds__(256)
void gemm_kernel(const bf16* __restrict__ nodes, const bf16* __restrict__ agg,
                 const bf16* __restrict__ WrT, const bf16* __restrict__ WlT,
                 const float* __restrict__ bias, float* __restrict__ out)
{
    __shared__ bf16 Alds[3][128 * 32];
    __shared__ bf16 Blds[3][128 * 32];
    const int t = threadIdx.x;
    const int lane = t & 63;
    const int w = t >> 6;
    const unsigned bid = blockIdx.x;
    const unsigned swz = (bid & 7) * 545 + (bid >> 3);
    const int bcol = swz & 7;
    int brow = (int)(swz >> 3);
    // mixed-brow spread + early dispatch: swap r <-> 68r+1 for r in 1..7.
    // Mixed (16-step) blocks land at positions {0,8,69,137,...,477}:
    // XCDs {0,0,1..7} and bids <= 568 -> all start in dispatch round 1.
    if (brow >= 1 && brow <= 7) brow = brow * 68 + 1;
    else if (brow >= 69 && brow <= 477 && ((brow - 1) % 68) == 0) brow = (brow - 1) / 68;

    f32x4 acc[4][4] = {};

    // staging: phys 16B slot s holds logical slot s ^ ((row>>1)&3)
    const int tq = t >> 2;                               // rows 0..63 (+64 for issue 1)
    const int kk = (((t & 3) ^ ((tq >> 1) & 3)) << 3);
    const int wr = (w >> 1) << 6;
    const int wc = (w & 1) << 6;
    const int fr = lane & 15;
    const int kq = lane >> 4;
    const int swzr = (kq ^ ((fr >> 1) & 3)) << 3;        // phys slot for reads (shorts)

    char* AldsB = (char*)Alds;
    char* BldsB = (char*)Blds;
    const short* AldsS = (const short*)Alds;
    const short* BldsS = (const short*)Blds;

    const int nsteps = (brow * 128 < N_NODES) ? 16 : 8;
    const bf16* Abase0 = nodes + (size_t)brow * 128 * C_DIM;
    const bf16* Abase1 = agg + (size_t)brow * 128 * C_DIM;
    const bf16* Bbase0 = WrT + (size_t)bcol * 128 * C_DIM;
    const bf16* Bbase1 = WlT + (size_t)bcol * 128 * C_DIM;

    auto STAGE = [&](int s, int buf) {
        const int k0 = (s & 7) * 32;
        const bf16* Ag = (s < 8 ? Abase0 : Abase1) + (size_t)tq * C_DIM + k0 + kk;
        const bf16* Bg = (s < 8 ? Bbase0 : Bbase1) + (size_t)tq * C_DIM + k0 + kk;
        gload16(AldsB + buf * 8192 + w * 1024,        Ag);
        gload16(AldsB + buf * 8192 + 4096 + w * 1024, Ag + 64 * C_DIM);
        gload16(BldsB + buf * 8192 + w * 1024,        Bg);
        gload16(BldsB + buf * 8192 + 4096 + w * 1024, Bg + 64 * C_DIM);
    };

    STAGE(0, 0);
    STAGE(1, 1);                       // 8 vmem ops in flight
    int rb = 0;
    for (int s = 0; s < nsteps; ++s) {
        if (s + 1 < nsteps) asm volatile("s_waitcnt vmcnt(4)" ::: "memory");
        else                asm volatile("s_waitcnt vmcnt(0)" ::: "memory");
        __builtin_amdgcn_s_barrier();
        if (s + 2 < nsteps) STAGE(s + 2, rb == 0 ? 2 : (rb == 1 ? 0 : 1));
        const short* Ab = AldsS + rb * 4096;
        const short* Bb = BldsS + rb * 4096;
        short8 av[4], bv[4];
#pragma unroll
        for (int m = 0; m < 4; ++m)
            av[m] = *(const short8*)(Ab + (wr + m * 16 + fr) * 32 + swzr);
#pragma unroll
        for (int n = 0; n < 4; ++n)
            bv[n] = *(const short8*)(Bb + (wc + n * 16 + fr) * 32 + swzr);
        // operand order swapped: first=bv, second=av -> transposed C/D roles
#pragma unroll
        for (int m = 0; m < 4; ++m)
#pragma unroll
            for (int n = 0; n < 4; ++n)
                acc[m][n] = __builtin_amdgcn_mfma_f32_16x16x32_bf16(
                    bv[n], av[m], acc[m][n], 0, 0, 0);
        rb = (rb == 2) ? 0 : rb + 1;
    }

    // ---- epilogue: bias + fast ELU + dwordx4 nontemporal stores ----
    const int r0 = brow * 128 + wr + fr;
    const unsigned bb0 = (unsigned)r0 / N_NODES;         // one divide per lane
    const int rsw = (int)((bb0 + 1) * N_NODES);
    float* outL = out + (size_t)(bcol >> 1) * CN;        // layer = bcol>>1 (uniform)
    const int cbase = (bcol & 1) * 128 + wc + kq * 4;    // col within layer
    f32x4 bi4[4];
#pragma unroll
    for (int n = 0; n < 4; ++n)
        bi4[n] = *(const f32x4*)(bias + bcol * 128 + wc + n * 16 + kq * 4);
#pragma unroll
    for (int m = 0; m < 4; ++m) {
        int r = r0 + m * 16;
        if (r < TOTAL) {
            int bb = (int)bb0 + (r >= rsw ? 1 : 0);
            int nn = r - bb * N_NODES;
            float* rowp = outL + (size_t)bb * OUT_STRIDE_B + (size_t)nn * C_DIM + cbase;
#pragma unroll
            for (int n = 0; n < 4; ++n) {
                f32x4 v = acc[m][n] + bi4[n];
                f32x4 o;
#pragma unroll
                for (int k = 0; k < 4; ++k)
                    o[k] = v[k] > 0.f ? v[k] : (__expf(v[k]) - 1.0f);
                __builtin_nontemporal_store(o, (f32x4*)(rowp + n * 16));
            }
        }
    }
}

extern "C" void kernel_launch(void* const* d_in, const int* in_sizes, int n_in,
                              void* d_out, int out_size, void* d_ws, size_t ws_size,
                              hipStream_t stream) {
    const float* x  = (const float*)d_in[0];
    const float* Wl = (const float*)d_in[1];
    const float* bl = (const float*)d_in[2];
    const float* Wr = (const float*)d_in[3];
    float* out = (float*)d_out;
    char* ws = (char*)d_ws;

    bf16* nodes = (bf16*)(ws + OFF_NODES);
    bf16* aggb  = (bf16*)(ws + OFF_AGGB);
    bf16* WlT   = (bf16*)(ws + OFF_WLT);
    bf16* WrT   = (bf16*)(ws + OFF_WRT);

    prep_kernel<<<128 + BATCH * 18 + 18, 256, 0, stream>>>(x, Wl, Wr, nodes, WlT, WrT, aggb, out);
    gemm_kernel<<<8 * 545, 256, 0, stream>>>(nodes, aggb, WrT, WlT, bl, out);
}

// Round 15
// 161.100 us; speedup vs baseline: 1.0901x; 1.0901x over previous
//
#include <hip/hip_runtime.h>
#include <hip/hip_bf16.h>
#include <stdint.h>

// StrideGraphSAGE on MI355X (gfx950).
// h_l = elu(agg @ Wl[l] + bl[l] + nodes @ Wr[l]); out = concat(h_0..h_3, x) along C.
// agg is nonzero only for rows < 1089; edge set = deterministic stride-2 grid.
//
// R15 = R9's verified 256^2 4-phase GEMM (BK=64, 8 waves, 128KB LDS, per-phase
// barriers, setprio, vmcnt(0)-before-closing-barrier, 3-bit XOR swizzle,
// bijective XCD swizzle) + R12's proven epilogue (swapped-operand MFMA ->
// dwordx4 nontemporal stores) + mixed-tile permutation q <-> 34q+1 (the 5
// double-work agg tiles spread to XCDs 0-4, all bids < 50 -> round 1).
// prep = R13's, gather = R9's (1280 rows, pad zeroed).

#define C_DIM 256
#define GRID_G 33
#define N_NODES 1089
#define BATCH 64
#define TOTAL (BATCH * N_NODES)     // 69696
#define M_PAD 69760
#define CN (C_DIM * N_NODES)        // 278784
#define OUT_STRIDE_B (5 * CN)       // 1393920
#define NCOLS 1024
#define AGG_ROWS_PAD 1280           // 5 tiles of 256; rows 1089..1279 zeroed
#define MT 273                      // ceil(69696/256)
#define NWG (MT * 4)                // 1092

using bf16 = __hip_bfloat16;
typedef __attribute__((ext_vector_type(8))) short short8;
typedef __attribute__((ext_vector_type(4))) float f32x4;

// ---- workspace layout (bytes) ----
#define NODES_BYTES ((size_t)M_PAD * C_DIM * 2)
#define OFF_NODES   ((size_t)0)
#define OFF_AGGB    (NODES_BYTES)
#define AGGB_BYTES  ((size_t)AGG_ROWS_PAD * C_DIM * 2)
#define OFF_WLT     (OFF_AGGB + AGGB_BYTES)
#define WT_BYTES    ((size_t)NCOLS * C_DIM * 2)
#define OFF_WRT     (OFF_WLT + WT_BYTES)

__device__ __forceinline__ void gload16(void* lds, const void* g) {
    __builtin_amdgcn_global_load_lds(
        (const __attribute__((address_space(1))) uint32_t*)g,
        (__attribute__((address_space(3))) uint32_t*)lds,
        16, 0, 0);
}

// ---- fused prep: blocks 0..127 W->WT bf16; 128..1279: x -> nodes + out block 4 ----
__global__ __launch_bounds__(256)
void prep_kernel(const float* __restrict__ x,
                 const float* __restrict__ Wl, const float* __restrict__ Wr,
                 bf16* __restrict__ nodes, bf16* __restrict__ WlT, bf16* __restrict__ WrT,
                 float* __restrict__ out)
{
    __shared__ char smem[33792];
    const int t = threadIdx.x;
    const int bid = blockIdx.x;
    if (bid < 128) {
        float (*tile)[65] = (float(*)[65])smem;
        const int sel = bid & 1;
        const int l = (bid >> 1) & 3;
        const int kt = ((bid >> 3) & 3) * 64;
        const int ct = ((bid >> 5) & 3) * 64;
        const float* W = sel ? Wr : Wl;
        bf16* WT = sel ? WrT : WlT;
        const int tc = t & 63;
        const int tk = t >> 6;
#pragma unroll
        for (int i = 0; i < 16; ++i) {
            int kl = i * 4 + tk;
            tile[kl][tc] = W[((size_t)(l * 256 + kt + kl)) * 256 + ct + tc];
        }
        __syncthreads();
#pragma unroll
        for (int i = 0; i < 16; ++i) {
            int cl = i * 4 + tk;
            WT[((size_t)(l * 256 + ct + cl)) * 256 + kt + tc] = __float2bfloat16(tile[tc][cl]);
        }
    } else {
        bf16 (*tile)[66] = (bf16(*)[66])smem;
        const int bid2 = bid - 128;
        const int b = bid2 / 18;
        const int n0 = (bid2 % 18) * 64;
        const int nl = t & 63;
        const int cs = t >> 6;
        const int n = n0 + nl;
        const bool nvalid = n < N_NODES;
        const float* xb = x + (size_t)b * CN;
        float* outb = out + (size_t)b * OUT_STRIDE_B + (size_t)4 * CN;
#pragma unroll 4
        for (int cc = 0; cc < 64; ++cc) {
            int c = cc * 4 + cs;
            if (nvalid) {
                float v = xb[(size_t)c * N_NODES + n];
                __builtin_nontemporal_store(v, &outb[(size_t)c * N_NODES + n]);
                tile[c][nl] = __float2bfloat16(v);
            }
        }
        __syncthreads();
        const int half = t >> 7;
        const int c0 = (t & 127) * 2;
#pragma unroll
        for (int it = 0; it < 32; ++it) {
            int row = it * 2 + half;
            int nr = n0 + row;
            if (nr < N_NODES) {
                __hip_bfloat162 p;
                p.x = tile[c0][row];
                p.y = tile[c0 + 1][row];
                *(__hip_bfloat162*)(nodes + ((size_t)b * N_NODES + nr) * C_DIM + c0) = p;
            }
        }
    }
}

// ---- analytic mean-aggregate; rows N_NODES..1279 zeroed ----
__global__ __launch_bounds__(256)
void gather_kernel(const bf16* __restrict__ nodes, bf16* __restrict__ aggb)
{
    const int n = blockIdx.x;        // 0..1279
    const int c = threadIdx.x;
    if (n >= N_NODES) {
        aggb[(size_t)n * C_DIM + c] = __float2bfloat16(0.f);
        return;
    }
    const int i = n / GRID_G, j = n % GRID_G;
    float s = 0.f, d = 0.f;
    if (j >= 2)           { s += __bfloat162float(nodes[(size_t)(n - 2)  * C_DIM + c]); d += 1.f; }
    if (i >= 2)           { s += __bfloat162float(nodes[(size_t)(n - 66) * C_DIM + c]); d += 1.f; }
    if (i >= 2 && j >= 2) { s += __bfloat162float(nodes[(size_t)(n - 68) * C_DIM + c]); d += 1.f; }
    if (i >= 2 && j >= 1 && j <= 30)
                          { s += __bfloat162float(nodes[(size_t)(n - 64) * C_DIM + c]); d += 1.f; }
    aggb[(size_t)n * C_DIM + c] = __float2bfloat16(d > 0.f ? s / d : 0.f);
}

// ---- 256^2 4-phase GEMM, swapped-operand MFMA, dwordx4 nt stores ----
// K-step kt: 0..3 = nodes@WrT; 4..7 = agg@WlT (brow<5 only). dbuf = kt&1.
__global__ __launch_bounds__(512)
void gemm_kernel(const bf16* __restrict__ nodes, const bf16* __restrict__ agg,
                 const bf16* __restrict__ WrT, const bf16* __restrict__ WlT,
                 const float* __restrict__ bias, float* __restrict__ out)
{
    extern __shared__ char Sb[];       // 131072: A[2][256][64] @0, B[2][256][64] @65536
    const int t = threadIdx.x;
    const int lane = t & 63;
    const int w = t >> 6;              // 0..7
    const int wm = w >> 2;             // 0..1
    const int wn = w & 3;              // 0..3
    const int fr = lane & 15;
    const int kq = lane >> 4;

    // bijective XCD swizzle: 1092 = 8*136 + 4 (m204).
    const unsigned bid = blockIdx.x;
    const unsigned xcd = bid & 7, loc = bid >> 3;
    const unsigned swz = (xcd < 4 ? xcd * 137u : 4u * 137u + (xcd - 4u) * 136u) + loc;
    const int bcol = swz & 3;          // == output layer
    int brow = (int)(swz >> 2);
    // mixed-tile spread + early dispatch: q <-> 34q+1 for q in 1..4.
    // Mixed tiles land at positions {0,35,69,103,137} -> XCDs {0,1,2,3,4}, bids<50.
    if (brow >= 1 && brow <= 4) brow = brow * 34 + 1;
    else if (brow >= 35 && brow <= 137 && ((brow - 1) % 34) == 0 && (brow - 1) / 34 <= 4)
        brow = (brow - 1) / 34;

    const int NT = (brow * 256 < N_NODES) ? 8 : 4;
    const size_t Arow0 = (size_t)brow * 256;
    const size_t Brow0 = (size_t)bcol * 256;

    f32x4 acc[8][4] = {};

    // staging: thread t covers row t>>3, phys slot t&7; inverse-swizzle SOURCE.
    const int srow = t >> 3;
    const int sk = (((t & 7) ^ (srow & 7)) << 3);
    // read-side: phys 16B slot = (ks*4+kq) ^ (row&7), row&7 == fr&7
    const int so0 = ((0 * 4 + kq) ^ (fr & 7)) << 4;
    const int so1 = ((1 * 4 + kq) ^ (fr & 7)) << 4;
    const int arow_b = (wm * 128 + fr) * 128;
    const int brow_b = (wn * 64 + fr) * 128;

    auto STAGE_HALF = [&](int kt, int half, int isB) {
        const int buf = kt & 1;
        const int kk0 = ((kt & 3) << 6) + sk;
        if (!isB) {
            const bf16* src = (kt < 4 ? nodes : agg);
            const size_t gr = Arow0 + half * 128 + srow;
            char* dst = Sb + buf * 32768 + half * 16384 + w * 1024;
            gload16(dst,        src + gr * 256 + kk0);
            gload16(dst + 8192, src + (gr + 64) * 256 + kk0);
        } else {
            const bf16* src = (kt < 4 ? WrT : WlT);
            const size_t gr = Brow0 + half * 128 + srow;
            char* dst = Sb + 65536 + buf * 32768 + half * 16384 + w * 1024;
            gload16(dst,        src + gr * 256 + kk0);
            gload16(dst + 8192, src + (gr + 64) * 256 + kk0);
        }
    };

    // prologue: stage kt0 + kt1 fully; wait kt0 (8 in flight); publish
    STAGE_HALF(0, 0, 0); STAGE_HALF(0, 1, 0); STAGE_HALF(0, 0, 1); STAGE_HALF(0, 1, 1);
    STAGE_HALF(1, 0, 0); STAGE_HALF(1, 1, 0); STAGE_HALF(1, 0, 1); STAGE_HALF(1, 1, 1);
    asm volatile("s_waitcnt vmcnt(8)" ::: "memory");
    __builtin_amdgcn_s_barrier();

    short8 av[4][2], bv0[2][2], bv1[2][2];

    for (int kt = 0; kt < NT; ++kt) {
        const int ab = (kt & 1) * 32768;
        const int bb = 65536 + (kt & 1) * 32768;
        const bool pf = (kt + 1 < NT);

        // ---- phase 0: (mh=0, nh=0) ----
#pragma unroll
        for (int i = 0; i < 4; ++i) {
            av[i][0] = *(const short8*)(Sb + ab + arow_b + i * 2048 + so0);
            av[i][1] = *(const short8*)(Sb + ab + arow_b + i * 2048 + so1);
        }
#pragma unroll
        for (int j = 0; j < 2; ++j) {
            bv0[j][0] = *(const short8*)(Sb + bb + brow_b + j * 2048 + so0);
            bv0[j][1] = *(const short8*)(Sb + bb + brow_b + j * 2048 + so1);
        }
        if (pf) STAGE_HALF(kt + 1, 0, 0);
        __builtin_amdgcn_s_barrier();
        asm volatile("s_waitcnt lgkmcnt(0)" ::: "memory");
        __builtin_amdgcn_sched_barrier(0);
        __builtin_amdgcn_s_setprio(1);
#pragma unroll
        for (int ks = 0; ks < 2; ++ks)
#pragma unroll
            for (int i = 0; i < 4; ++i)
#pragma unroll
                for (int j = 0; j < 2; ++j)
                    acc[i][j] = __builtin_amdgcn_mfma_f32_16x16x32_bf16(
                        bv0[j][ks], av[i][ks], acc[i][j], 0, 0, 0);
        __builtin_amdgcn_s_setprio(0);
        __builtin_amdgcn_s_barrier();

        // ---- phase 1: (0,1) ----
#pragma unroll
        for (int j = 0; j < 2; ++j) {
            bv1[j][0] = *(const short8*)(Sb + bb + brow_b + 4096 + j * 2048 + so0);
            bv1[j][1] = *(const short8*)(Sb + bb + brow_b + 4096 + j * 2048 + so1);
        }
        if (pf) STAGE_HALF(kt + 1, 1, 0);
        __builtin_amdgcn_s_barrier();
        asm volatile("s_waitcnt lgkmcnt(0)" ::: "memory");
        __builtin_amdgcn_sched_barrier(0);
        __builtin_amdgcn_s_setprio(1);
#pragma unroll
        for (int ks = 0; ks < 2; ++ks)
#pragma unroll
            for (int i = 0; i < 4; ++i)
#pragma unroll
                for (int j = 0; j < 2; ++j)
                    acc[i][2 + j] = __builtin_amdgcn_mfma_f32_16x16x32_bf16(
                        bv1[j][ks], av[i][ks], acc[i][2 + j], 0, 0, 0);
        __builtin_amdgcn_s_setprio(0);
        __builtin_amdgcn_s_barrier();

        // ---- phase 2: (1,1) ----
#pragma unroll
        for (int i = 0; i < 4; ++i) {
            av[i][0] = *(const short8*)(Sb + ab + arow_b + 8192 + i * 2048 + so0);
            av[i][1] = *(const short8*)(Sb + ab + arow_b + 8192 + i * 2048 + so1);
        }
        if (pf) STAGE_HALF(kt + 1, 0, 1);
        __builtin_amdgcn_s_barrier();
        asm volatile("s_waitcnt lgkmcnt(0)" ::: "memory");
        __builtin_amdgcn_sched_barrier(0);
        __builtin_amdgcn_s_setprio(1);
#pragma unroll
        for (int ks = 0; ks < 2; ++ks)
#pragma unroll
            for (int i = 0; i < 4; ++i)
#pragma unroll
                for (int j = 0; j < 2; ++j)
                    acc[4 + i][2 + j] = __builtin_amdgcn_mfma_f32_16x16x32_bf16(
                        bv1[j][ks], av[i][ks], acc[4 + i][2 + j], 0, 0, 0);
        __builtin_amdgcn_s_setprio(0);
        __builtin_amdgcn_s_barrier();

        // ---- phase 3: (1,0) no reads ----
        if (pf) STAGE_HALF(kt + 1, 1, 1);
        __builtin_amdgcn_s_barrier();
        __builtin_amdgcn_s_setprio(1);
#pragma unroll
        for (int ks = 0; ks < 2; ++ks)
#pragma unroll
            for (int i = 0; i < 4; ++i)
#pragma unroll
                for (int j = 0; j < 2; ++j)
                    acc[4 + i][j] = __builtin_amdgcn_mfma_f32_16x16x32_bf16(
                        bv0[j][ks], av[i][ks], acc[4 + i][j], 0, 0, 0);
        __builtin_amdgcn_s_setprio(0);
        if (pf) asm volatile("s_waitcnt vmcnt(0)" ::: "memory");
        __builtin_amdgcn_s_barrier();
    }

    // ---- epilogue: bias + fast ELU + dwordx4 nontemporal stores ----
    // swapped-operand C/D map: row = brow*256 + wm*128 + I*16 + fr,
    // cols = bcol*256 + wn*64 + J*16 + kq*4 + {0..3}
    const int r0 = brow * 256 + wm * 128 + fr;
    const unsigned bb0 = (unsigned)r0 / N_NODES;
    const int rsw = (int)((bb0 + 1) * N_NODES);
    float* outL = out + (size_t)bcol * CN;
    const int cbase = wn * 64 + kq * 4;
    f32x4 bi4[4];
#pragma unroll
    for (int J = 0; J < 4; ++J)
        bi4[J] = *(const f32x4*)(bias + bcol * 256 + wn * 64 + J * 16 + kq * 4);
#pragma unroll
    for (int I = 0; I < 8; ++I) {
        int r = r0 + I * 16;
        if (r < TOTAL) {
            int bb = (int)bb0 + (r >= rsw ? 1 : 0);
            int nn = r - bb * N_NODES;
            float* rowp = outL + (size_t)bb * OUT_STRIDE_B + (size_t)nn * C_DIM + cbase;
#pragma unroll
            for (int J = 0; J < 4; ++J) {
                f32x4 v = acc[I][J] + bi4[J];
                f32x4 o;
#pragma unroll
                for (int k = 0; k < 4; ++k)
                    o[k] = v[k] > 0.f ? v[k] : (__expf(v[k]) - 1.0f);
                __builtin_nontemporal_store(o, (f32x4*)(rowp + J * 16));
            }
        }
    }
}

extern "C" void kernel_launch(void* const* d_in, const int* in_sizes, int n_in,
                              void* d_out, int out_size, void* d_ws, size_t ws_size,
                              hipStream_t stream) {
    const float* x  = (const float*)d_in[0];
    const float* Wl = (const float*)d_in[1];
    const float* bl = (const float*)d_in[2];
    const float* Wr = (const float*)d_in[3];
    float* out = (float*)d_out;
    char* ws = (char*)d_ws;

    bf16* nodes = (bf16*)(ws + OFF_NODES);
    bf16* aggb  = (bf16*)(ws + OFF_AGGB);
    bf16* WlT   = (bf16*)(ws + OFF_WLT);
    bf16* WrT   = (bf16*)(ws + OFF_WRT);

    prep_kernel<<<128 + BATCH * 18, 256, 0, stream>>>(x, Wl, Wr, nodes, WlT, WrT, out);
    gather_kernel<<<AGG_ROWS_PAD, 256, 0, stream>>>(nodes, aggb);
    gemm_kernel<<<NWG, 512, 131072, stream>>>(nodes, aggb, WrT, WlT, bl, out);
}

// Round 16
// 135.639 us; speedup vs baseline: 1.2947x; 1.1877x over previous
//
#include <hip/hip_runtime.h>
#include <hip/hip_bf16.h>
#include <stdint.h>

// StrideGraphSAGE on MI355X (gfx950).
// h_l = elu(agg @ Wl[l] + bl[l] + nodes @ Wr[l]); out = concat(h_0..h_3, x) along C.
// agg is nonzero only for rows < 1089; edge set = deterministic stride-2 grid.
//
// R16 = R13 EXACT (swapped-operand MFMA dwordx4 nt stores; 128^2, 3-ring,
// counted vmcnt(4), XCD swizzle) with ONE change, unbundled from R14:
// mixed-brow permutation r <-> 68r+1 (r in 1..7) instead of r <-> 61r.
// The nine 16-step (agg-mixed) blocks land at positions {0,8,69,...,477}:
// XCDs {0,0,1..7} (balanced, same as R13) AND bids <= 568 < 768 -> all start
// in dispatch round 1, removing the 8-step straggler tail R13 created.

#define C_DIM 256
#define GRID_G 33
#define N_NODES 1089
#define BATCH 64
#define TOTAL (BATCH * N_NODES)     // 69696
#define M_PAD 69760
#define CN (C_DIM * N_NODES)        // 278784
#define OUT_STRIDE_B (5 * CN)       // 1393920
#define NCOLS 1024
#define AGG_ROWS 1152               // 9 tiles of 128; rows 1089..1151 zeroed

using bf16 = __hip_bfloat16;
typedef __attribute__((ext_vector_type(8))) short short8;
typedef __attribute__((ext_vector_type(4))) float f32x4;

// ---- workspace layout (bytes) ----
#define NODES_BYTES ((size_t)M_PAD * C_DIM * 2)
#define OFF_NODES   ((size_t)0)
#define OFF_AGGB    (NODES_BYTES)
#define AGGB_BYTES  ((size_t)AGG_ROWS * C_DIM * 2)
#define OFF_WLT     (OFF_AGGB + AGGB_BYTES)
#define WT_BYTES    ((size_t)NCOLS * C_DIM * 2)
#define OFF_WRT     (OFF_WLT + WT_BYTES)

__device__ __forceinline__ void gload16(void* lds, const void* g) {
    __builtin_amdgcn_global_load_lds(
        (const __attribute__((address_space(1))) uint32_t*)g,
        (__attribute__((address_space(3))) uint32_t*)lds,
        16, 0, 0);
}

// ---- fused prep: blocks 0..127 W->WT bf16; 128..1279: x -> nodes + out block 4 ----
__global__ __launch_bounds__(256)
void prep_kernel(const float* __restrict__ x,
                 const float* __restrict__ Wl, const float* __restrict__ Wr,
                 bf16* __restrict__ nodes, bf16* __restrict__ WlT, bf16* __restrict__ WrT,
                 float* __restrict__ out)
{
    __shared__ char smem[33792];
    const int t = threadIdx.x;
    const int bid = blockIdx.x;
    if (bid < 128) {
        float (*tile)[65] = (float(*)[65])smem;
        const int sel = bid & 1;
        const int l = (bid >> 1) & 3;
        const int kt = ((bid >> 3) & 3) * 64;
        const int ct = ((bid >> 5) & 3) * 64;
        const float* W = sel ? Wr : Wl;
        bf16* WT = sel ? WrT : WlT;
        const int tc = t & 63;
        const int tk = t >> 6;
#pragma unroll
        for (int i = 0; i < 16; ++i) {
            int kl = i * 4 + tk;
            tile[kl][tc] = W[((size_t)(l * 256 + kt + kl)) * 256 + ct + tc];
        }
        __syncthreads();
#pragma unroll
        for (int i = 0; i < 16; ++i) {
            int cl = i * 4 + tk;
            WT[((size_t)(l * 256 + ct + cl)) * 256 + kt + tc] = __float2bfloat16(tile[tc][cl]);
        }
    } else {
        bf16 (*tile)[66] = (bf16(*)[66])smem;
        const int bid2 = bid - 128;
        const int b = bid2 / 18;
        const int n0 = (bid2 % 18) * 64;
        const int nl = t & 63;
        const int cs = t >> 6;
        const int n = n0 + nl;
        const bool nvalid = n < N_NODES;
        const float* xb = x + (size_t)b * CN;
        float* outb = out + (size_t)b * OUT_STRIDE_B + (size_t)4 * CN;
#pragma unroll 4
        for (int cc = 0; cc < 64; ++cc) {
            int c = cc * 4 + cs;
            if (nvalid) {
                float v = xb[(size_t)c * N_NODES + n];
                __builtin_nontemporal_store(v, &outb[(size_t)c * N_NODES + n]);
                tile[c][nl] = __float2bfloat16(v);
            }
        }
        __syncthreads();
        const int half = t >> 7;
        const int c0 = (t & 127) * 2;
#pragma unroll
        for (int it = 0; it < 32; ++it) {
            int row = it * 2 + half;
            int nr = n0 + row;
            if (nr < N_NODES) {
                __hip_bfloat162 p;
                p.x = tile[c0][row];
                p.y = tile[c0 + 1][row];
                *(__hip_bfloat162*)(nodes + ((size_t)b * N_NODES + nr) * C_DIM + c0) = p;
            }
        }
    }
}

// ---- analytic mean-aggregate; rows N_NODES..1151 zeroed ----
__global__ __launch_bounds__(256)
void gather_kernel(const bf16* __restrict__ nodes, bf16* __restrict__ aggb)
{
    const int n = blockIdx.x;        // 0..1151
    const int c = threadIdx.x;
    if (n >= N_NODES) {
        aggb[(size_t)n * C_DIM + c] = __float2bfloat16(0.f);
        return;
    }
    const int i = n / GRID_G, j = n % GRID_G;
    float s = 0.f, d = 0.f;
    if (j >= 2)           { s += __bfloat162float(nodes[(size_t)(n - 2)  * C_DIM + c]); d += 1.f; }
    if (i >= 2)           { s += __bfloat162float(nodes[(size_t)(n - 66) * C_DIM + c]); d += 1.f; }
    if (i >= 2 && j >= 2) { s += __bfloat162float(nodes[(size_t)(n - 68) * C_DIM + c]); d += 1.f; }
    if (i >= 2 && j >= 1 && j <= 30)
                          { s += __bfloat162float(nodes[(size_t)(n - 64) * C_DIM + c]); d += 1.f; }
    aggb[(size_t)n * C_DIM + c] = __float2bfloat16(d > 0.f ? s / d : 0.f);
}

// ---- fused GEMM: out = elu(nodes@WrT^T + [agg@WlT^T] + bias), dwordx4 stores ----
// 128x128 tile, 4 waves, 16x16x32 bf16 MFMA. 3-buffer LDS, 2-deep prefetch,
// counted s_waitcnt vmcnt(4) + raw s_barrier. XOR-swizzled LDS both-sides.
// XCD-aware block swizzle + early-dispatch mixed-brow permutation (r <-> 68r+1).
// MFMA operands swapped: acc[m][n] f32x4 = out[row brow*128+wr+m*16+fr]
// [cols bcol*128+wc+n*16+kq*4 .. +3] -> dwordx4 nontemporal stores.
__global__ __launch_bounds__(256)
void gemm_kernel(const bf16* __restrict__ nodes, const bf16* __restrict__ agg,
                 const bf16* __restrict__ WrT, const bf16* __restrict__ WlT,
                 const float* __restrict__ bias, float* __restrict__ out)
{
    __shared__ bf16 Alds[3][128 * 32];
    __shared__ bf16 Blds[3][128 * 32];
    const int t = threadIdx.x;
    const int lane = t & 63;
    const int w = t >> 6;
    const unsigned bid = blockIdx.x;
    const unsigned swz = (bid & 7) * 545 + (bid >> 3);
    const int bcol = swz & 7;
    int brow = (int)(swz >> 3);
    // mixed-brow spread + early dispatch: swap r <-> 68r+1 for r in 1..7.
    // Mixed (16-step) blocks land at positions {0,8,69,137,...,477}:
    // XCDs {0,0,1..7} and bids <= 568 -> all start in dispatch round 1.
    if (brow >= 1 && brow <= 7) brow = brow * 68 + 1;
    else if (brow >= 69 && brow <= 477 && ((brow - 1) % 68) == 0) brow = (brow - 1) / 68;

    f32x4 acc[4][4] = {};

    // staging: phys 16B slot s holds logical slot s ^ ((row>>1)&3)
    const int tq = t >> 2;                               // rows 0..63 (+64 for issue 1)
    const int kk = (((t & 3) ^ ((tq >> 1) & 3)) << 3);
    const int wr = (w >> 1) << 6;
    const int wc = (w & 1) << 6;
    const int fr = lane & 15;
    const int kq = lane >> 4;
    const int swzr = (kq ^ ((fr >> 1) & 3)) << 3;        // phys slot for reads (shorts)

    char* AldsB = (char*)Alds;
    char* BldsB = (char*)Blds;
    const short* AldsS = (const short*)Alds;
    const short* BldsS = (const short*)Blds;

    const int nsteps = (brow * 128 < N_NODES) ? 16 : 8;
    const bf16* Abase0 = nodes + (size_t)brow * 128 * C_DIM;
    const bf16* Abase1 = agg + (size_t)brow * 128 * C_DIM;
    const bf16* Bbase0 = WrT + (size_t)bcol * 128 * C_DIM;
    const bf16* Bbase1 = WlT + (size_t)bcol * 128 * C_DIM;

    auto STAGE = [&](int s, int buf) {
        const int k0 = (s & 7) * 32;
        const bf16* Ag = (s < 8 ? Abase0 : Abase1) + (size_t)tq * C_DIM + k0 + kk;
        const bf16* Bg = (s < 8 ? Bbase0 : Bbase1) + (size_t)tq * C_DIM + k0 + kk;
        gload16(AldsB + buf * 8192 + w * 1024,        Ag);
        gload16(AldsB + buf * 8192 + 4096 + w * 1024, Ag + 64 * C_DIM);
        gload16(BldsB + buf * 8192 + w * 1024,        Bg);
        gload16(BldsB + buf * 8192 + 4096 + w * 1024, Bg + 64 * C_DIM);
    };

    STAGE(0, 0);
    STAGE(1, 1);                       // 8 vmem ops in flight
    int rb = 0;
    for (int s = 0; s < nsteps; ++s) {
        if (s + 1 < nsteps) asm volatile("s_waitcnt vmcnt(4)" ::: "memory");
        else                asm volatile("s_waitcnt vmcnt(0)" ::: "memory");
        __builtin_amdgcn_s_barrier();
        if (s + 2 < nsteps) STAGE(s + 2, rb == 0 ? 2 : (rb == 1 ? 0 : 1));
        const short* Ab = AldsS + rb * 4096;
        const short* Bb = BldsS + rb * 4096;
        short8 av[4], bv[4];
#pragma unroll
        for (int m = 0; m < 4; ++m)
            av[m] = *(const short8*)(Ab + (wr + m * 16 + fr) * 32 + swzr);
#pragma unroll
        for (int n = 0; n < 4; ++n)
            bv[n] = *(const short8*)(Bb + (wc + n * 16 + fr) * 32 + swzr);
        // operand order swapped: first=bv, second=av -> transposed C/D roles
#pragma unroll
        for (int m = 0; m < 4; ++m)
#pragma unroll
            for (int n = 0; n < 4; ++n)
                acc[m][n] = __builtin_amdgcn_mfma_f32_16x16x32_bf16(
                    bv[n], av[m], acc[m][n], 0, 0, 0);
        rb = (rb == 2) ? 0 : rb + 1;
    }

    // ---- epilogue: bias + fast ELU + dwordx4 nontemporal stores ----
    const int r0 = brow * 128 + wr + fr;
    const unsigned bb0 = (unsigned)r0 / N_NODES;         // one divide per lane
    const int rsw = (int)((bb0 + 1) * N_NODES);
    float* outL = out + (size_t)(bcol >> 1) * CN;        // layer = bcol>>1 (uniform)
    const int cbase = (bcol & 1) * 128 + wc + kq * 4;    // col within layer
    f32x4 bi4[4];
#pragma unroll
    for (int n = 0; n < 4; ++n)
        bi4[n] = *(const f32x4*)(bias + bcol * 128 + wc + n * 16 + kq * 4);
#pragma unroll
    for (int m = 0; m < 4; ++m) {
        int r = r0 + m * 16;
        if (r < TOTAL) {
            int bb = (int)bb0 + (r >= rsw ? 1 : 0);
            int nn = r - bb * N_NODES;
            float* rowp = outL + (size_t)bb * OUT_STRIDE_B + (size_t)nn * C_DIM + cbase;
#pragma unroll
            for (int n = 0; n < 4; ++n) {
                f32x4 v = acc[m][n] + bi4[n];
                f32x4 o;
#pragma unroll
                for (int k = 0; k < 4; ++k)
                    o[k] = v[k] > 0.f ? v[k] : (__expf(v[k]) - 1.0f);
                __builtin_nontemporal_store(o, (f32x4*)(rowp + n * 16));
            }
        }
    }
}

extern "C" void kernel_launch(void* const* d_in, const int* in_sizes, int n_in,
                              void* d_out, int out_size, void* d_ws, size_t ws_size,
                              hipStream_t stream) {
    const float* x  = (const float*)d_in[0];
    const float* Wl = (const float*)d_in[1];
    const float* bl = (const float*)d_in[2];
    const float* Wr = (const float*)d_in[3];
    float* out = (float*)d_out;
    char* ws = (char*)d_ws;

    bf16* nodes = (bf16*)(ws + OFF_NODES);
    bf16* aggb  = (bf16*)(ws + OFF_AGGB);
    bf16* WlT   = (bf16*)(ws + OFF_WLT);
    bf16* WrT   = (bf16*)(ws + OFF_WRT);

    prep_kernel<<<128 + BATCH * 18, 256, 0, stream>>>(x, Wl, Wr, nodes, WlT, WrT, out);
    gather_kernel<<<AGG_ROWS, 256, 0, stream>>>(nodes, aggb);
    gemm_kernel<<<8 * 545, 256, 0, stream>>>(nodes, aggb, WrT, WlT, bl, out);
}